// Round 6
// baseline (211.107 us; speedup 1.0000x reference)
//
#include <hip/hip_runtime.h>
#include <math.h>

#define Bdim 64
#define Ndim 512
#define Ddim 16
#define Kdim 16
#define Edim 128
#define LN_EPS 1e-5f

#define PTS   2     // points per block, ONE point per wave
#define NT    8     // 16-wide N tiles over E=128
#define KS2   4     // 32-deep K steps over E=128

typedef __attribute__((ext_vector_type(8))) short bf16x8;
typedef __attribute__((ext_vector_type(4))) float f32x4;

#if __has_builtin(__builtin_amdgcn_exp2f)
#define EXP2F __builtin_amdgcn_exp2f
#else
#define EXP2F exp2f
#endif

// RNE float -> bf16 bits (used only in the tiny pack kernel)
__device__ __forceinline__ unsigned short f2bf(float f) {
    unsigned u = __float_as_uint(f);
    unsigned r = (u + 0x7FFFu + ((u >> 16) & 1u)) >> 16;
    return (unsigned short)r;
}

// HW packed f32->bf16 (RNE): lo16 = bf16(a), hi16 = bf16(b)
__device__ __forceinline__ unsigned cvt_pk_bf16(float a, float b) {
    unsigned r;
    asm("v_cvt_pk_bf16_f32 %0, %1, %2" : "=v"(r) : "v"(a), "v"(b));
    return r;
}

// GELU tanh-form via sigmoid; exp folded to native 2^x:
// gelu(x) ~= x * rcp(1 + 2^(x * (-2.30220821 - 0.10294324 x^2)))
__device__ __forceinline__ float gelu_fast(float x) {
    float x2 = x * x;
    float t  = fmaf(x2, -0.10294324f, -2.30220821f);
    float e  = EXP2F(x * t);
    return x * __builtin_amdgcn_rcpf(1.0f + e);
}

// ---------------- weight pre-pack: fp32 row-major [K][128] -> bf16 B-fragments
// layout: [nt][ks][lane][j], fragment elem j of lane l = W[ks*32 + 8*(l>>4)+j][nt*16 + (l&15)]
__global__ __launch_bounds__(256) void pack_w_kernel(
    const float* __restrict__ W1, const float* __restrict__ W2,
    const float* __restrict__ W3, unsigned short* __restrict__ wp)
{
    int idx = blockIdx.x * 256 + threadIdx.x;
    if (idx >= 36864) return;
    if (idx < 4096) {
        int t = idx;
        int nt = t >> 9, l = (t >> 3) & 63, j = t & 7;
        int k = 8 * (l >> 4) + j, n = nt * 16 + (l & 15);
        wp[idx] = f2bf(W1[k * Edim + n]);
    } else if (idx < 20480) {
        int t = idx - 4096;
        int nt = t >> 11, ks = (t >> 9) & 3, l = (t >> 3) & 63, j = t & 7;
        int k = ks * 32 + 8 * (l >> 4) + j, n = nt * 16 + (l & 15);
        wp[idx] = f2bf(W2[k * Edim + n]);
    } else {
        int t = idx - 20480;
        int nt = t >> 11, ks = (t >> 9) & 3, l = (t >> 3) & 63, j = t & 7;
        int k = ks * 32 + 8 * (l >> 4) + j, n = nt * 16 + (l & 15);
        wp[idx] = f2bf(W3[k * Edim + n]);
    }
}

// LayerNorm + GELU on the wave-private accumulator (one point).
// D layout per 16x16 tile: value j of lane l is H[row = 4*(l>>4) + j][col = nt*16 + (l&15)]
__device__ __forceinline__ void ln_gelu_acc(
    f32x4 acc[NT], const float* __restrict__ g, const float* __restrict__ be, int lane)
{
    const int cl = lane & 15;
    float s[4] = {0.f,0.f,0.f,0.f}, s2[4] = {0.f,0.f,0.f,0.f};
    #pragma unroll
    for (int nt = 0; nt < NT; ++nt)
        #pragma unroll
        for (int j = 0; j < 4; ++j) {
            float v = acc[nt][j];
            s[j] += v;
            s2[j] = fmaf(v, v, s2[j]);
        }
    #pragma unroll
    for (int off = 1; off < 16; off <<= 1)
        #pragma unroll
        for (int j = 0; j < 4; ++j) {
            s[j]  += __shfl_xor(s[j],  off, 64);
            s2[j] += __shfl_xor(s2[j], off, 64);
        }
    float mj[4], rj[4];
    #pragma unroll
    for (int j = 0; j < 4; ++j) {
        float m   = s[j]  * (1.0f/128.0f);
        float var = s2[j] * (1.0f/128.0f) - m * m;
        mj[j] = m;
        rj[j] = __builtin_amdgcn_rsqf(var + LN_EPS);
    }
    #pragma unroll
    for (int nt = 0; nt < NT; ++nt) {
        const float gv = g[nt*16 + cl], bev = be[nt*16 + cl];
        #pragma unroll
        for (int j = 0; j < 4; ++j) {
            float v = (acc[nt][j] - mj[j]) * rj[j];
            v = fmaf(v, gv, bev);
            acc[nt][j] = gelu_fast(v);
        }
    }
}

// store acc (bf16 via HW cvt_pk) to swizzled H:
// elem col c of row r lives at r*128 + ((c>>3 ^ (r&7))<<3) + (c&7)
__device__ __forceinline__ void store_h(
    const f32x4 acc[NT], unsigned short* __restrict__ s_h, int wave, int lane)
{
    const int cl = lane & 15, gq = lane >> 4;
    const int rbase = 16*wave + 4*gq;
    #pragma unroll
    for (int nt = 0; nt < NT; ++nt) {
        const int col = nt*16 + cl;
        const int cb  = col >> 3;
        const unsigned r01 = cvt_pk_bf16(acc[nt][0], acc[nt][1]);
        const unsigned r23 = cvt_pk_bf16(acc[nt][2], acc[nt][3]);
        const int a0 = (rbase+0)*128 + ((cb ^ ((rbase+0) & 7)) << 3) + (col & 7);
        const int a1 = (rbase+1)*128 + ((cb ^ ((rbase+1) & 7)) << 3) + (col & 7);
        const int a2 = (rbase+2)*128 + ((cb ^ ((rbase+2) & 7)) << 3) + (col & 7);
        const int a3 = (rbase+3)*128 + ((cb ^ ((rbase+3) & 7)) << 3) + (col & 7);
        s_h[a0] = (unsigned short)(r01 & 0xFFFFu);
        s_h[a1] = (unsigned short)(r01 >> 16);
        s_h[a2] = (unsigned short)(r23 & 0xFFFFu);
        s_h[a3] = (unsigned short)(r23 >> 16);
    }
}

__global__ __launch_bounds__(128, 4) void edgeconv_mfma(
    const float* __restrict__ x,
    const unsigned short* __restrict__ wp,
    const float* __restrict__ b1, const float* __restrict__ g1, const float* __restrict__ be1,
    const float* __restrict__ b2, const float* __restrict__ g2, const float* __restrict__ be2,
    const float* __restrict__ b3, const float* __restrict__ g3, const float* __restrict__ be3,
    float* __restrict__ out)
{
    const int tid  = threadIdx.x;
    const int wave = tid >> 6, lane = tid & 63;
    const int bp = blockIdx.x;
    const int b  = bp >> 8;              // 256 blocks per batch element
    const int n0 = (bp & 255) * PTS;
    const int n  = n0 + wave;            // this wave's point

    // only LDS: wave-private H rows (wave w owns rows 16w..16w+15). No barriers anywhere.
    __shared__ __align__(16) unsigned short s_h[32 * 128];         // 8 KB, XOR-swizzled

    const float* __restrict__ xb = x + (size_t)b * (Ndim * Ddim);
    const int cl = lane & 15, gq = lane >> 4;

    // ---- KNN for this wave's point. Exact fp32 mul/mul/add; ties by lower idx.
    //      Lane cl captures the cl-th selected neighbor index in my_nb.
    unsigned my_nb = 0;
    {
        const float qx = xb[n * Ddim + 8], qy = xb[n * Ddim + 9];
        unsigned long long key[8];
        #pragma unroll
        for (int c = 0; c < 8; ++c) {
            int j = c * 64 + lane;
            const float2 p2 = *(const float2*)(xb + j * Ddim + 8);
            float dx = __fsub_rn(qx, p2.x);
            float dy = __fsub_rn(qy, p2.y);
            float d2 = __fadd_rn(__fmul_rn(dx,dx), __fmul_rn(dy,dy));
            key[c] = ((unsigned long long)__float_as_uint(d2) << 32) | (unsigned)j;
        }
        // lane-local ascending sort of 8 keys (Batcher odd-even mergesort, 19 CE)
        #define CE(A,B) { bool c_ = key[A] < key[B];                          \
                          unsigned long long lo_ = c_ ? key[A] : key[B];      \
                          unsigned long long hi_ = c_ ? key[B] : key[A];      \
                          key[A] = lo_; key[B] = hi_; }
        CE(0,1) CE(2,3) CE(4,5) CE(6,7)
        CE(0,2) CE(1,3) CE(4,6) CE(5,7)
        CE(1,2) CE(5,6)
        CE(0,4) CE(1,5) CE(2,6) CE(3,7)
        CE(2,4) CE(3,5)
        CE(1,2) CE(3,4) CE(5,6)
        #undef CE

        for (int sel = 0; sel < Kdim; ++sel) {
            unsigned long long m = key[0];          // lane-local current min (sorted head)
            #pragma unroll
            for (int off = 32; off > 0; off >>= 1) {
                unsigned long long o = __shfl_xor(m, off, 64);
                m = (o < m) ? o : m;
            }
            unsigned widx = (unsigned)m;
            if ((lane & 15) == sel) my_nb = widx;   // capture for all 4 gq quads
            const bool owner = ((widx & 63u) == (unsigned)lane);
            if (owner) {                            // pop sorted head (static indices)
                key[0] = key[1]; key[1] = key[2]; key[2] = key[3]; key[3] = key[4];
                key[4] = key[5]; key[5] = key[6]; key[6] = key[7]; key[7] = ~0ull;
            }
        }
    }

    f32x4 acc[NT];

    // ================= Layer 1: feats(16x32) @ W1, A-fragment built in registers =================
    {
        const int off8 = (gq & 1) * 8;
        const float* pc = xb + n * Ddim + off8;
        const float* pn = xb + (int)my_nb * Ddim + off8;
        float4 c0 = *(const float4*)(pc);
        float4 c1 = *(const float4*)(pc + 4);
        float4 v0 = *(const float4*)(pn);
        float4 v1 = *(const float4*)(pn + 4);
        const bool diff = (gq >= 2);
        float e0 = diff ? (v0.x - c0.x) : c0.x;
        float e1 = diff ? (v0.y - c0.y) : c0.y;
        float e2 = diff ? (v0.z - c0.z) : c0.z;
        float e3 = diff ? (v0.w - c0.w) : c0.w;
        float e4 = diff ? (v1.x - c1.x) : c1.x;
        float e5 = diff ? (v1.y - c1.y) : c1.y;
        float e6 = diff ? (v1.z - c1.z) : c1.z;
        float e7 = diff ? (v1.w - c1.w) : c1.w;
        union { unsigned u[4]; bf16x8 v; } a1u;
        a1u.u[0] = cvt_pk_bf16(e0, e1);
        a1u.u[1] = cvt_pk_bf16(e2, e3);
        a1u.u[2] = cvt_pk_bf16(e4, e5);
        a1u.u[3] = cvt_pk_bf16(e6, e7);
        const bf16x8 a1 = a1u.v;

        #pragma unroll
        for (int nt = 0; nt < NT; ++nt) {
            const float bv = b1[nt*16 + cl];
            bf16x8 bfr = *(const bf16x8*)(wp + (nt*64 + lane)*8);
            f32x4 c = {bv, bv, bv, bv};
            acc[nt] = __builtin_amdgcn_mfma_f32_16x16x32_bf16(a1, bfr, c, 0, 0, 0);
        }
    }
    ln_gelu_acc(acc, g1, be1, lane);
    store_h(acc, s_h, wave, lane);

    // ================= Layers 2 and 3: H(16x128) @ W(128x128) =================
    #pragma unroll 1
    for (int layer = 0; layer < 2; ++layer) {
        const unsigned short* wpL = wp + (layer == 0 ? 4096 : 20480);
        const float* bL  = (layer == 0) ? b2  : b3;
        const float* gL  = (layer == 0) ? g2  : g3;
        const float* beL = (layer == 0) ? be2 : be3;

        bf16x8 a[KS2];
        {
            const int row = 16*wave + cl;
            #pragma unroll
            for (int ks = 0; ks < KS2; ++ks) {
                const int cb = ks*4 + gq;
                a[ks] = *(const bf16x8*)(&s_h[row*128 + ((cb ^ (row & 7)) << 3)]);
            }
        }
        #pragma unroll
        for (int nt = 0; nt < NT; ++nt) {
            const float bv = bL[nt*16 + cl];
            f32x4 c = {bv, bv, bv, bv};
            #pragma unroll
            for (int ks = 0; ks < KS2; ++ks) {
                bf16x8 bfr = *(const bf16x8*)(wpL + ((nt*KS2 + ks)*64 + lane)*8);
                c = __builtin_amdgcn_mfma_f32_16x16x32_bf16(a[ks], bfr, c, 0, 0, 0);
            }
            acc[nt] = c;
        }
        ln_gelu_acc(acc, gL, beL, lane);
        if (layer == 0) store_h(acc, s_h, wave, lane);
    }

    // ================= mean over K=16 rows, write out =================
    #pragma unroll
    for (int nt = 0; nt < NT; ++nt) {
        float sv = acc[nt][0] + acc[nt][1] + acc[nt][2] + acc[nt][3];
        sv += __shfl_xor(sv, 16, 64);
        sv += __shfl_xor(sv, 32, 64);
        if (gq == (nt >> 1))    // 16 lanes of the owning quad write 64B
            out[((size_t)b * Ndim + n) * Edim + nt*16 + cl] = sv * (1.0f/16.0f);
    }
}

extern "C" void kernel_launch(void* const* d_in, const int* in_sizes, int n_in,
                              void* d_out, int out_size, void* d_ws, size_t ws_size,
                              hipStream_t stream)
{
    const float* x   = (const float*)d_in[0];
    const float* W1  = (const float*)d_in[1];
    const float* b1  = (const float*)d_in[2];
    const float* g1  = (const float*)d_in[3];
    const float* be1 = (const float*)d_in[4];
    const float* W2  = (const float*)d_in[5];
    const float* b2  = (const float*)d_in[6];
    const float* g2  = (const float*)d_in[7];
    const float* be2 = (const float*)d_in[8];
    const float* W3  = (const float*)d_in[9];
    const float* b3  = (const float*)d_in[10];
    const float* g3  = (const float*)d_in[11];
    const float* be3 = (const float*)d_in[12];
    float* out = (float*)d_out;
    unsigned short* wp = (unsigned short*)d_ws;

    hipLaunchKernelGGL(pack_w_kernel, dim3(144), dim3(256), 0, stream, W1, W2, W3, wp);
    hipLaunchKernelGGL(edgeconv_mfma, dim3((Bdim * Ndim) / PTS), dim3(128), 0, stream,
                       x, wp, b1, g1, be1, b2, g2, be2, b3, g3, be3, out);
}

// Round 7
// 168.522 us; speedup vs baseline: 1.2527x; 1.2527x over previous
//
#include <hip/hip_runtime.h>
#include <math.h>

#define Bdim 64
#define Ndim 512
#define Ddim 16
#define Kdim 16
#define Edim 128
#define LN_EPS 1e-5f

#define PTS   2     // points per block, ONE point per wave
#define NT    8     // 16-wide N tiles over E=128
#define KS2   4     // 32-deep K steps over E=128

typedef __attribute__((ext_vector_type(8))) short bf16x8;
typedef __attribute__((ext_vector_type(4))) float f32x4;

#if __has_builtin(__builtin_amdgcn_exp2f)
#define EXP2F __builtin_amdgcn_exp2f
#else
#define EXP2F exp2f
#endif

// ---- DPP helpers: row_ror rotations within 16-lane rows (pure VALU, no LDS) ----
// ctrl: row_ror:N = 0x120 | N
template<int CTRL>
__device__ __forceinline__ unsigned dpp_u32(unsigned v) {
    return (unsigned)__builtin_amdgcn_update_dpp(0, (int)v, CTRL, 0xF, 0xF, true);
}
template<int CTRL>
__device__ __forceinline__ float dpp_f32(float v) {
    return __int_as_float(__builtin_amdgcn_update_dpp(0, __float_as_int(v), CTRL, 0xF, 0xF, true));
}
template<int CTRL>
__device__ __forceinline__ unsigned long long dpp_u64(unsigned long long v) {
    unsigned lo = dpp_u32<CTRL>((unsigned)v);
    unsigned hi = dpp_u32<CTRL>((unsigned)(v >> 32));
    return ((unsigned long long)hi << 32) | lo;
}
__device__ __forceinline__ unsigned long long min_u64(unsigned long long a, unsigned long long b) {
    return (b < a) ? b : a;
}

// RNE float -> bf16 bits (used only in the tiny pack kernel)
__device__ __forceinline__ unsigned short f2bf(float f) {
    unsigned u = __float_as_uint(f);
    unsigned r = (u + 0x7FFFu + ((u >> 16) & 1u)) >> 16;
    return (unsigned short)r;
}

// HW packed f32->bf16 (RNE): lo16 = bf16(a), hi16 = bf16(b)
__device__ __forceinline__ unsigned cvt_pk_bf16(float a, float b) {
    unsigned r;
    asm("v_cvt_pk_bf16_f32 %0, %1, %2" : "=v"(r) : "v"(a), "v"(b));
    return r;
}

// GELU tanh-form via sigmoid; exp folded to native 2^x:
// gelu(x) ~= x * rcp(1 + 2^(x * (-2.30220821 - 0.10294324 x^2)))
__device__ __forceinline__ float gelu_fast(float x) {
    float x2 = x * x;
    float t  = fmaf(x2, -0.10294324f, -2.30220821f);
    float e  = EXP2F(x * t);
    return x * __builtin_amdgcn_rcpf(1.0f + e);
}

// ---------------- weight pre-pack: fp32 row-major [K][128] -> bf16 B-fragments
// layout: [nt][ks][lane][j], fragment elem j of lane l = W[ks*32 + 8*(l>>4)+j][nt*16 + (l&15)]
__global__ __launch_bounds__(256) void pack_w_kernel(
    const float* __restrict__ W1, const float* __restrict__ W2,
    const float* __restrict__ W3, unsigned short* __restrict__ wp)
{
    int idx = blockIdx.x * 256 + threadIdx.x;
    if (idx >= 36864) return;
    if (idx < 4096) {
        int t = idx;
        int nt = t >> 9, l = (t >> 3) & 63, j = t & 7;
        int k = 8 * (l >> 4) + j, n = nt * 16 + (l & 15);
        wp[idx] = f2bf(W1[k * Edim + n]);
    } else if (idx < 20480) {
        int t = idx - 4096;
        int nt = t >> 11, ks = (t >> 9) & 3, l = (t >> 3) & 63, j = t & 7;
        int k = ks * 32 + 8 * (l >> 4) + j, n = nt * 16 + (l & 15);
        wp[idx] = f2bf(W2[k * Edim + n]);
    } else {
        int t = idx - 20480;
        int nt = t >> 11, ks = (t >> 9) & 3, l = (t >> 3) & 63, j = t & 7;
        int k = ks * 32 + 8 * (l >> 4) + j, n = nt * 16 + (l & 15);
        wp[idx] = f2bf(W3[k * Edim + n]);
    }
}

// LayerNorm + GELU on the wave-private accumulator (one point).
// D layout per 16x16 tile: value j of lane l is H[row = 4*(l>>4) + j][col = nt*16 + (l&15)]
// Reduction over the 16 lanes of a row via DPP rot-adds (no LDS traffic).
__device__ __forceinline__ void ln_gelu_acc(
    f32x4 acc[NT], const float* __restrict__ g, const float* __restrict__ be, int lane)
{
    const int cl = lane & 15;
    float s[4] = {0.f,0.f,0.f,0.f}, s2[4] = {0.f,0.f,0.f,0.f};
    #pragma unroll
    for (int nt = 0; nt < NT; ++nt)
        #pragma unroll
        for (int j = 0; j < 4; ++j) {
            float v = acc[nt][j];
            s[j] += v;
            s2[j] = fmaf(v, v, s2[j]);
        }
    #pragma unroll
    for (int j = 0; j < 4; ++j) {
        s[j]  += dpp_f32<0x121>(s[j]);   s2[j] += dpp_f32<0x121>(s2[j]);  // rot 1
        s[j]  += dpp_f32<0x122>(s[j]);   s2[j] += dpp_f32<0x122>(s2[j]);  // rot 2
        s[j]  += dpp_f32<0x124>(s[j]);   s2[j] += dpp_f32<0x124>(s2[j]);  // rot 4
        s[j]  += dpp_f32<0x128>(s[j]);   s2[j] += dpp_f32<0x128>(s2[j]);  // rot 8
    }
    float mj[4], rj[4];
    #pragma unroll
    for (int j = 0; j < 4; ++j) {
        float m   = s[j]  * (1.0f/128.0f);
        float var = s2[j] * (1.0f/128.0f) - m * m;
        mj[j] = m;
        rj[j] = __builtin_amdgcn_rsqf(var + LN_EPS);
    }
    #pragma unroll
    for (int nt = 0; nt < NT; ++nt) {
        const float gv = g[nt*16 + cl], bev = be[nt*16 + cl];
        #pragma unroll
        for (int j = 0; j < 4; ++j) {
            float v = (acc[nt][j] - mj[j]) * rj[j];
            v = fmaf(v, gv, bev);
            acc[nt][j] = gelu_fast(v);
        }
    }
}

// store acc (bf16 via HW cvt_pk) to swizzled H:
// elem col c of row r lives at r*128 + ((c>>3 ^ (r&7))<<3) + (c&7)
__device__ __forceinline__ void store_h(
    const f32x4 acc[NT], unsigned short* __restrict__ s_h, int wave, int lane)
{
    const int cl = lane & 15, gq = lane >> 4;
    const int rbase = 16*wave + 4*gq;
    #pragma unroll
    for (int nt = 0; nt < NT; ++nt) {
        const int col = nt*16 + cl;
        const int cb  = col >> 3;
        const unsigned r01 = cvt_pk_bf16(acc[nt][0], acc[nt][1]);
        const unsigned r23 = cvt_pk_bf16(acc[nt][2], acc[nt][3]);
        const int a0 = (rbase+0)*128 + ((cb ^ ((rbase+0) & 7)) << 3) + (col & 7);
        const int a1 = (rbase+1)*128 + ((cb ^ ((rbase+1) & 7)) << 3) + (col & 7);
        const int a2 = (rbase+2)*128 + ((cb ^ ((rbase+2) & 7)) << 3) + (col & 7);
        const int a3 = (rbase+3)*128 + ((cb ^ ((rbase+3) & 7)) << 3) + (col & 7);
        s_h[a0] = (unsigned short)(r01 & 0xFFFFu);
        s_h[a1] = (unsigned short)(r01 >> 16);
        s_h[a2] = (unsigned short)(r23 & 0xFFFFu);
        s_h[a3] = (unsigned short)(r23 >> 16);
    }
}

__global__ __launch_bounds__(128, 4) void edgeconv_mfma(
    const float* __restrict__ x,
    const unsigned short* __restrict__ wp,
    const float* __restrict__ b1, const float* __restrict__ g1, const float* __restrict__ be1,
    const float* __restrict__ b2, const float* __restrict__ g2, const float* __restrict__ be2,
    const float* __restrict__ b3, const float* __restrict__ g3, const float* __restrict__ be3,
    float* __restrict__ out)
{
    const int tid  = threadIdx.x;
    const int wave = tid >> 6, lane = tid & 63;
    const int bp = blockIdx.x;
    const int b  = bp >> 8;              // 256 blocks per batch element
    const int n0 = (bp & 255) * PTS;
    const int n  = n0 + wave;            // this wave's point

    // only LDS: wave-private H rows (wave w owns rows 16w..16w+15). No barriers anywhere.
    __shared__ __align__(16) unsigned short s_h[32 * 128];         // 8 KB, XOR-swizzled

    const float* __restrict__ xb = x + (size_t)b * (Ndim * Ddim);
    const int cl = lane & 15, gq = lane >> 4;

    // ---- KNN for this wave's point. Exact fp32 mul/mul/add; ties by lower idx.
    //      Lane cl captures the cl-th selected neighbor index in my_nb.
    unsigned my_nb = 0;
    {
        const float qx = xb[n * Ddim + 8], qy = xb[n * Ddim + 9];
        unsigned long long key[8];
        #pragma unroll
        for (int c = 0; c < 8; ++c) {
            int j = c * 64 + lane;
            const float2 p2 = *(const float2*)(xb + j * Ddim + 8);
            float dx = __fsub_rn(qx, p2.x);
            float dy = __fsub_rn(qy, p2.y);
            float d2 = __fadd_rn(__fmul_rn(dx,dx), __fmul_rn(dy,dy));
            key[c] = ((unsigned long long)__float_as_uint(d2) << 32) | (unsigned)j;
        }
        // lane-local ascending sort of 8 keys (Batcher odd-even mergesort, 19 CE)
        #define CE(A,B) { bool c_ = key[A] < key[B];                          \
                          unsigned long long lo_ = c_ ? key[A] : key[B];      \
                          unsigned long long hi_ = c_ ? key[B] : key[A];      \
                          key[A] = lo_; key[B] = hi_; }
        CE(0,1) CE(2,3) CE(4,5) CE(6,7)
        CE(0,2) CE(1,3) CE(4,6) CE(5,7)
        CE(1,2) CE(5,6)
        CE(0,4) CE(1,5) CE(2,6) CE(3,7)
        CE(2,4) CE(3,5)
        CE(1,2) CE(3,4) CE(5,6)
        #undef CE

        for (int sel = 0; sel < Kdim; ++sel) {
            unsigned long long m = key[0];          // lane-local current min (sorted head)
            // intra-row min via DPP rotations (VALU only)
            m = min_u64(m, dpp_u64<0x121>(m));
            m = min_u64(m, dpp_u64<0x122>(m));
            m = min_u64(m, dpp_u64<0x124>(m));
            m = min_u64(m, dpp_u64<0x128>(m));
            // cross-row: xor 16, then 32
            m = min_u64(m, (unsigned long long)__shfl_xor(m, 16, 64));
            m = min_u64(m, (unsigned long long)__shfl_xor(m, 32, 64));
            unsigned widx = (unsigned)m;
            if ((lane & 15) == sel) my_nb = widx;   // capture for all 4 gq quads
            const bool owner = ((widx & 63u) == (unsigned)lane);
            if (owner) {                            // pop sorted head (static indices)
                key[0] = key[1]; key[1] = key[2]; key[2] = key[3]; key[3] = key[4];
                key[4] = key[5]; key[5] = key[6]; key[6] = key[7]; key[7] = ~0ull;
            }
        }
    }

    f32x4 acc[NT];

    // ================= Layer 1: feats(16x32) @ W1, A-fragment built in registers =================
    {
        const int off8 = (gq & 1) * 8;
        const float* pc = xb + n * Ddim + off8;
        const float* pn = xb + (int)my_nb * Ddim + off8;
        float4 c0 = *(const float4*)(pc);
        float4 c1 = *(const float4*)(pc + 4);
        float4 v0 = *(const float4*)(pn);
        float4 v1 = *(const float4*)(pn + 4);
        const bool diff = (gq >= 2);
        float e0 = diff ? (v0.x - c0.x) : c0.x;
        float e1 = diff ? (v0.y - c0.y) : c0.y;
        float e2 = diff ? (v0.z - c0.z) : c0.z;
        float e3 = diff ? (v0.w - c0.w) : c0.w;
        float e4 = diff ? (v1.x - c1.x) : c1.x;
        float e5 = diff ? (v1.y - c1.y) : c1.y;
        float e6 = diff ? (v1.z - c1.z) : c1.z;
        float e7 = diff ? (v1.w - c1.w) : c1.w;
        union { unsigned u[4]; bf16x8 v; } a1u;
        a1u.u[0] = cvt_pk_bf16(e0, e1);
        a1u.u[1] = cvt_pk_bf16(e2, e3);
        a1u.u[2] = cvt_pk_bf16(e4, e5);
        a1u.u[3] = cvt_pk_bf16(e6, e7);
        const bf16x8 a1 = a1u.v;

        #pragma unroll
        for (int nt = 0; nt < NT; ++nt) {
            const float bv = b1[nt*16 + cl];
            bf16x8 bfr = *(const bf16x8*)(wp + (nt*64 + lane)*8);
            f32x4 c = {bv, bv, bv, bv};
            acc[nt] = __builtin_amdgcn_mfma_f32_16x16x32_bf16(a1, bfr, c, 0, 0, 0);
        }
    }
    ln_gelu_acc(acc, g1, be1, lane);
    store_h(acc, s_h, wave, lane);

    // ================= Layers 2 and 3: H(16x128) @ W(128x128) =================
    #pragma unroll 1
    for (int layer = 0; layer < 2; ++layer) {
        const unsigned short* wpL = wp + (layer == 0 ? 4096 : 20480);
        const float* bL  = (layer == 0) ? b2  : b3;
        const float* gL  = (layer == 0) ? g2  : g3;
        const float* beL = (layer == 0) ? be2 : be3;

        bf16x8 a[KS2];
        {
            const int row = 16*wave + cl;
            #pragma unroll
            for (int ks = 0; ks < KS2; ++ks) {
                const int cb = ks*4 + gq;
                a[ks] = *(const bf16x8*)(&s_h[row*128 + ((cb ^ (row & 7)) << 3)]);
            }
        }
        #pragma unroll
        for (int nt = 0; nt < NT; ++nt) {
            const float bv = bL[nt*16 + cl];
            f32x4 c = {bv, bv, bv, bv};
            #pragma unroll
            for (int ks = 0; ks < KS2; ++ks) {
                bf16x8 bfr = *(const bf16x8*)(wpL + ((nt*KS2 + ks)*64 + lane)*8);
                c = __builtin_amdgcn_mfma_f32_16x16x32_bf16(a[ks], bfr, c, 0, 0, 0);
            }
            acc[nt] = c;
        }
        ln_gelu_acc(acc, gL, beL, lane);
        if (layer == 0) store_h(acc, s_h, wave, lane);
    }

    // ================= mean over K=16 rows, write out =================
    #pragma unroll
    for (int nt = 0; nt < NT; ++nt) {
        float sv = acc[nt][0] + acc[nt][1] + acc[nt][2] + acc[nt][3];
        sv += __shfl_xor(sv, 16, 64);
        sv += __shfl_xor(sv, 32, 64);
        if (gq == (nt >> 1))    // 16 lanes of the owning quad write 64B
            out[((size_t)b * Ndim + n) * Edim + nt*16 + cl] = sv * (1.0f/16.0f);
    }
}

extern "C" void kernel_launch(void* const* d_in, const int* in_sizes, int n_in,
                              void* d_out, int out_size, void* d_ws, size_t ws_size,
                              hipStream_t stream)
{
    const float* x   = (const float*)d_in[0];
    const float* W1  = (const float*)d_in[1];
    const float* b1  = (const float*)d_in[2];
    const float* g1  = (const float*)d_in[3];
    const float* be1 = (const float*)d_in[4];
    const float* W2  = (const float*)d_in[5];
    const float* b2  = (const float*)d_in[6];
    const float* g2  = (const float*)d_in[7];
    const float* be2 = (const float*)d_in[8];
    const float* W3  = (const float*)d_in[9];
    const float* b3  = (const float*)d_in[10];
    const float* g3  = (const float*)d_in[11];
    const float* be3 = (const float*)d_in[12];
    float* out = (float*)d_out;
    unsigned short* wp = (unsigned short*)d_ws;

    hipLaunchKernelGGL(pack_w_kernel, dim3(144), dim3(256), 0, stream, W1, W2, W3, wp);
    hipLaunchKernelGGL(edgeconv_mfma, dim3((Bdim * Ndim) / PTS), dim3(128), 0, stream,
                       x, wp, b1, g1, be1, b2, g2, be2, b3, g3, be3, out);
}

// Round 8
// 161.499 us; speedup vs baseline: 1.3072x; 1.0435x over previous
//
#include <hip/hip_runtime.h>
#include <math.h>

#define Bdim 64
#define Ndim 512
#define Ddim 16
#define Kdim 16
#define Edim 128
#define LN_EPS 1e-5f

#define PTS   2     // points per block, ONE point per wave
#define NT    8     // 16-wide N tiles over E=128
#define KS2   4     // 32-deep K steps over E=128

typedef __attribute__((ext_vector_type(8))) short bf16x8;
typedef __attribute__((ext_vector_type(4))) float f32x4;
typedef __attribute__((ext_vector_type(2))) float f32x2;

#if __has_builtin(__builtin_amdgcn_exp2f)
#define EXP2F __builtin_amdgcn_exp2f
#else
#define EXP2F exp2f
#endif

// ---- DPP helpers: row_ror rotations within 16-lane rows (pure VALU, no LDS) ----
// ctrl: row_ror:N = 0x120 | N
template<int CTRL>
__device__ __forceinline__ unsigned dpp_u32(unsigned v) {
    return (unsigned)__builtin_amdgcn_update_dpp(0, (int)v, CTRL, 0xF, 0xF, true);
}
template<int CTRL>
__device__ __forceinline__ float dpp_f32(float v) {
    return __int_as_float(__builtin_amdgcn_update_dpp(0, __float_as_int(v), CTRL, 0xF, 0xF, true));
}
template<int CTRL>
__device__ __forceinline__ unsigned long long dpp_u64(unsigned long long v) {
    unsigned lo = dpp_u32<CTRL>((unsigned)v);
    unsigned hi = dpp_u32<CTRL>((unsigned)(v >> 32));
    return ((unsigned long long)hi << 32) | lo;
}
__device__ __forceinline__ unsigned long long min_u64(unsigned long long a, unsigned long long b) {
    return (b < a) ? b : a;
}

// RNE float -> bf16 bits (used only in the tiny pack kernel)
__device__ __forceinline__ unsigned short f2bf(float f) {
    unsigned u = __float_as_uint(f);
    unsigned r = (u + 0x7FFFu + ((u >> 16) & 1u)) >> 16;
    return (unsigned short)r;
}

// HW packed f32->bf16 (RNE): lo16 = bf16(a), hi16 = bf16(b)
__device__ __forceinline__ unsigned cvt_pk_bf16(float a, float b) {
    unsigned r;
    asm("v_cvt_pk_bf16_f32 %0, %1, %2" : "=v"(r) : "v"(a), "v"(b));
    return r;
}

// packed GELU (tanh-form via sigmoid, exp folded to native 2^x):
// gelu(x) ~= x * rcp(1 + 2^(x * (-2.30220821 - 0.10294324 x^2)))
// all f32x2 math maps to v_pk_mul/v_pk_fma/v_pk_add; exp2/rcp stay scalar TRANS.
__device__ __forceinline__ f32x2 gelu2(f32x2 x) {
    f32x2 x2 = x * x;
    f32x2 t  = x2 * (f32x2){-0.10294324f, -0.10294324f}
                  + (f32x2){-2.30220821f, -2.30220821f};
    f32x2 z  = x * t;
    f32x2 e  = { EXP2F(z.x), EXP2F(z.y) };
    f32x2 d  = e + (f32x2){1.0f, 1.0f};
    f32x2 r  = { __builtin_amdgcn_rcpf(d.x), __builtin_amdgcn_rcpf(d.y) };
    return x * r;
}

// ---------------- weight pre-pack: fp32 row-major [K][128] -> bf16 B-fragments
// layout: [nt][ks][lane][j], fragment elem j of lane l = W[ks*32 + 8*(l>>4)+j][nt*16 + (l&15)]
__global__ __launch_bounds__(256) void pack_w_kernel(
    const float* __restrict__ W1, const float* __restrict__ W2,
    const float* __restrict__ W3, unsigned short* __restrict__ wp)
{
    int idx = blockIdx.x * 256 + threadIdx.x;
    if (idx >= 36864) return;
    if (idx < 4096) {
        int t = idx;
        int nt = t >> 9, l = (t >> 3) & 63, j = t & 7;
        int k = 8 * (l >> 4) + j, n = nt * 16 + (l & 15);
        wp[idx] = f2bf(W1[k * Edim + n]);
    } else if (idx < 20480) {
        int t = idx - 4096;
        int nt = t >> 11, ks = (t >> 9) & 3, l = (t >> 3) & 63, j = t & 7;
        int k = ks * 32 + 8 * (l >> 4) + j, n = nt * 16 + (l & 15);
        wp[idx] = f2bf(W2[k * Edim + n]);
    } else {
        int t = idx - 20480;
        int nt = t >> 11, ks = (t >> 9) & 3, l = (t >> 3) & 63, j = t & 7;
        int k = ks * 32 + 8 * (l >> 4) + j, n = nt * 16 + (l & 15);
        wp[idx] = f2bf(W3[k * Edim + n]);
    }
}

// LayerNorm + GELU on the wave-private accumulator (one point).
// D layout per 16x16 tile: value j of lane l is H[row = 4*(l>>4) + j][col = nt*16 + (l&15)]
// Row-reduction via DPP rot-adds; elementwise math on packed f32x2 (v_pk_*).
__device__ __forceinline__ void ln_gelu_acc(
    f32x4 acc[NT], const float* __restrict__ g, const float* __restrict__ be, int lane)
{
    const int cl = lane & 15;
    f32x2 s01 = {0.f,0.f}, s23 = {0.f,0.f}, q01 = {0.f,0.f}, q23 = {0.f,0.f};
    #pragma unroll
    for (int nt = 0; nt < NT; ++nt) {
        f32x2 a01 = { acc[nt][0], acc[nt][1] };
        f32x2 a23 = { acc[nt][2], acc[nt][3] };
        s01 += a01;  q01 += a01 * a01;      // pk_add / pk_fma
        s23 += a23;  q23 += a23 * a23;
    }
    float s[4]  = { s01.x, s01.y, s23.x, s23.y };
    float s2[4] = { q01.x, q01.y, q23.x, q23.y };
    #pragma unroll
    for (int j = 0; j < 4; ++j) {
        s[j]  += dpp_f32<0x121>(s[j]);   s2[j] += dpp_f32<0x121>(s2[j]);  // rot 1
        s[j]  += dpp_f32<0x122>(s[j]);   s2[j] += dpp_f32<0x122>(s2[j]);  // rot 2
        s[j]  += dpp_f32<0x124>(s[j]);   s2[j] += dpp_f32<0x124>(s2[j]);  // rot 4
        s[j]  += dpp_f32<0x128>(s[j]);   s2[j] += dpp_f32<0x128>(s2[j]);  // rot 8
    }
    float mj[4], rj[4];
    #pragma unroll
    for (int j = 0; j < 4; ++j) {
        float m   = s[j]  * (1.0f/128.0f);
        float var = s2[j] * (1.0f/128.0f) - m * m;
        mj[j] = m;
        rj[j] = __builtin_amdgcn_rsqf(var + LN_EPS);
    }
    const f32x2 m01 = { mj[0], mj[1] }, m23 = { mj[2], mj[3] };
    const f32x2 r01 = { rj[0], rj[1] }, r23 = { rj[2], rj[3] };
    #pragma unroll
    for (int nt = 0; nt < NT; ++nt) {
        const float gv = g[nt*16 + cl], bev = be[nt*16 + cl];
        const f32x2 gg = { gv, gv }, bb = { bev, bev };
        f32x2 a01 = { acc[nt][0], acc[nt][1] };
        f32x2 a23 = { acc[nt][2], acc[nt][3] };
        f32x2 v01 = (a01 - m01) * r01;      // pk_sub + pk_mul (same per-elem order as before)
        f32x2 v23 = (a23 - m23) * r23;
        v01 = v01 * gg + bb;                // pk_fma
        v23 = v23 * gg + bb;
        f32x2 w01 = gelu2(v01);
        f32x2 w23 = gelu2(v23);
        acc[nt][0] = w01.x; acc[nt][1] = w01.y;
        acc[nt][2] = w23.x; acc[nt][3] = w23.y;
    }
}

// store acc (bf16 via HW cvt_pk) to swizzled H:
// elem col c of row r lives at r*128 + ((c>>3 ^ (r&7))<<3) + (c&7)
__device__ __forceinline__ void store_h(
    const f32x4 acc[NT], unsigned short* __restrict__ s_h, int wave, int lane)
{
    const int cl = lane & 15, gq = lane >> 4;
    const int rbase = 16*wave + 4*gq;
    #pragma unroll
    for (int nt = 0; nt < NT; ++nt) {
        const int col = nt*16 + cl;
        const int cb  = col >> 3;
        const unsigned r01 = cvt_pk_bf16(acc[nt][0], acc[nt][1]);
        const unsigned r23 = cvt_pk_bf16(acc[nt][2], acc[nt][3]);
        const int a0 = (rbase+0)*128 + ((cb ^ ((rbase+0) & 7)) << 3) + (col & 7);
        const int a1 = (rbase+1)*128 + ((cb ^ ((rbase+1) & 7)) << 3) + (col & 7);
        const int a2 = (rbase+2)*128 + ((cb ^ ((rbase+2) & 7)) << 3) + (col & 7);
        const int a3 = (rbase+3)*128 + ((cb ^ ((rbase+3) & 7)) << 3) + (col & 7);
        s_h[a0] = (unsigned short)(r01 & 0xFFFFu);
        s_h[a1] = (unsigned short)(r01 >> 16);
        s_h[a2] = (unsigned short)(r23 & 0xFFFFu);
        s_h[a3] = (unsigned short)(r23 >> 16);
    }
}

__global__ __launch_bounds__(128, 4) void edgeconv_mfma(
    const float* __restrict__ x,
    const unsigned short* __restrict__ wp,
    const float* __restrict__ b1, const float* __restrict__ g1, const float* __restrict__ be1,
    const float* __restrict__ b2, const float* __restrict__ g2, const float* __restrict__ be2,
    const float* __restrict__ b3, const float* __restrict__ g3, const float* __restrict__ be3,
    float* __restrict__ out)
{
    const int tid  = threadIdx.x;
    const int wave = tid >> 6, lane = tid & 63;
    const int bp = blockIdx.x;
    const int b  = bp >> 8;              // 256 blocks per batch element
    const int n0 = (bp & 255) * PTS;
    const int n  = n0 + wave;            // this wave's point

    // only LDS: wave-private H rows (wave w owns rows 16w..16w+15). No barriers anywhere.
    __shared__ __align__(16) unsigned short s_h[32 * 128];         // 8 KB, XOR-swizzled

    const float* __restrict__ xb = x + (size_t)b * (Ndim * Ddim);
    const int cl = lane & 15, gq = lane >> 4;

    // ---- KNN for this wave's point. Exact fp32 mul/mul/add; ties by lower idx.
    //      Lane cl captures the cl-th selected neighbor index in my_nb.
    unsigned my_nb = 0;
    {
        const float qx = xb[n * Ddim + 8], qy = xb[n * Ddim + 9];
        unsigned long long key[8];
        #pragma unroll
        for (int c = 0; c < 8; ++c) {
            int j = c * 64 + lane;
            const float2 p2 = *(const float2*)(xb + j * Ddim + 8);
            float dx = __fsub_rn(qx, p2.x);
            float dy = __fsub_rn(qy, p2.y);
            float d2 = __fadd_rn(__fmul_rn(dx,dx), __fmul_rn(dy,dy));
            key[c] = ((unsigned long long)__float_as_uint(d2) << 32) | (unsigned)j;
        }
        // lane-local ascending sort of 8 keys (Batcher odd-even mergesort, 19 CE)
        #define CE(A,B) { bool c_ = key[A] < key[B];                          \
                          unsigned long long lo_ = c_ ? key[A] : key[B];      \
                          unsigned long long hi_ = c_ ? key[B] : key[A];      \
                          key[A] = lo_; key[B] = hi_; }
        CE(0,1) CE(2,3) CE(4,5) CE(6,7)
        CE(0,2) CE(1,3) CE(4,6) CE(5,7)
        CE(1,2) CE(5,6)
        CE(0,4) CE(1,5) CE(2,6) CE(3,7)
        CE(2,4) CE(3,5)
        CE(1,2) CE(3,4) CE(5,6)
        #undef CE

        for (int sel = 0; sel < Kdim; ++sel) {
            unsigned long long m = key[0];          // lane-local current min (sorted head)
            // intra-row min via DPP rotations (VALU only)
            m = min_u64(m, dpp_u64<0x121>(m));
            m = min_u64(m, dpp_u64<0x122>(m));
            m = min_u64(m, dpp_u64<0x124>(m));
            m = min_u64(m, dpp_u64<0x128>(m));
            // cross-row: xor 16, then 32 (LDS pipe — off the saturated VALU pipe)
            m = min_u64(m, (unsigned long long)__shfl_xor(m, 16, 64));
            m = min_u64(m, (unsigned long long)__shfl_xor(m, 32, 64));
            unsigned widx = (unsigned)m;
            if ((lane & 15) == sel) my_nb = widx;   // capture for all 4 gq quads
            const bool owner = ((widx & 63u) == (unsigned)lane);
            if (owner) {                            // pop sorted head (static indices)
                key[0] = key[1]; key[1] = key[2]; key[2] = key[3]; key[3] = key[4];
                key[4] = key[5]; key[5] = key[6]; key[6] = key[7]; key[7] = ~0ull;
            }
        }
    }

    f32x4 acc[NT];

    // ================= Layer 1: feats(16x32) @ W1, A-fragment built in registers =================
    {
        const int off8 = (gq & 1) * 8;
        const float* pc = xb + n * Ddim + off8;
        const float* pn = xb + (int)my_nb * Ddim + off8;
        float4 c0 = *(const float4*)(pc);
        float4 c1 = *(const float4*)(pc + 4);
        float4 v0 = *(const float4*)(pn);
        float4 v1 = *(const float4*)(pn + 4);
        const bool diff = (gq >= 2);
        float e0 = diff ? (v0.x - c0.x) : c0.x;
        float e1 = diff ? (v0.y - c0.y) : c0.y;
        float e2 = diff ? (v0.z - c0.z) : c0.z;
        float e3 = diff ? (v0.w - c0.w) : c0.w;
        float e4 = diff ? (v1.x - c1.x) : c1.x;
        float e5 = diff ? (v1.y - c1.y) : c1.y;
        float e6 = diff ? (v1.z - c1.z) : c1.z;
        float e7 = diff ? (v1.w - c1.w) : c1.w;
        union { unsigned u[4]; bf16x8 v; } a1u;
        a1u.u[0] = cvt_pk_bf16(e0, e1);
        a1u.u[1] = cvt_pk_bf16(e2, e3);
        a1u.u[2] = cvt_pk_bf16(e4, e5);
        a1u.u[3] = cvt_pk_bf16(e6, e7);
        const bf16x8 a1 = a1u.v;

        #pragma unroll
        for (int nt = 0; nt < NT; ++nt) {
            const float bv = b1[nt*16 + cl];
            bf16x8 bfr = *(const bf16x8*)(wp + (nt*64 + lane)*8);
            f32x4 c = {bv, bv, bv, bv};
            acc[nt] = __builtin_amdgcn_mfma_f32_16x16x32_bf16(a1, bfr, c, 0, 0, 0);
        }
    }
    ln_gelu_acc(acc, g1, be1, lane);
    store_h(acc, s_h, wave, lane);

    // ================= Layers 2 and 3: H(16x128) @ W(128x128) =================
    #pragma unroll 1
    for (int layer = 0; layer < 2; ++layer) {
        const unsigned short* wpL = wp + (layer == 0 ? 4096 : 20480);
        const float* bL  = (layer == 0) ? b2  : b3;
        const float* gL  = (layer == 0) ? g2  : g3;
        const float* beL = (layer == 0) ? be2 : be3;

        bf16x8 a[KS2];
        {
            const int row = 16*wave + cl;
            #pragma unroll
            for (int ks = 0; ks < KS2; ++ks) {
                const int cb = ks*4 + gq;
                a[ks] = *(const bf16x8*)(&s_h[row*128 + ((cb ^ (row & 7)) << 3)]);
            }
        }
        #pragma unroll
        for (int nt = 0; nt < NT; ++nt) {
            const float bv = bL[nt*16 + cl];
            f32x4 c = {bv, bv, bv, bv};
            #pragma unroll
            for (int ks = 0; ks < KS2; ++ks) {
                bf16x8 bfr = *(const bf16x8*)(wpL + ((nt*KS2 + ks)*64 + lane)*8);
                c = __builtin_amdgcn_mfma_f32_16x16x32_bf16(a[ks], bfr, c, 0, 0, 0);
            }
            acc[nt] = c;
        }
        ln_gelu_acc(acc, gL, beL, lane);
        if (layer == 0) store_h(acc, s_h, wave, lane);
    }

    // ================= mean over K=16 rows, write out =================
    #pragma unroll
    for (int nt = 0; nt < NT; ++nt) {
        f32x2 p = { acc[nt][0], acc[nt][1] };
        f32x2 q = { acc[nt][2], acc[nt][3] };
        f32x2 h = p + q;                    // pk_add
        float sv = h.x + h.y;
        sv += __shfl_xor(sv, 16, 64);
        sv += __shfl_xor(sv, 32, 64);
        if (gq == (nt >> 1))    // 16 lanes of the owning quad write 64B
            out[((size_t)b * Ndim + n) * Edim + nt*16 + cl] = sv * (1.0f/16.0f);
    }
}

extern "C" void kernel_launch(void* const* d_in, const int* in_sizes, int n_in,
                              void* d_out, int out_size, void* d_ws, size_t ws_size,
                              hipStream_t stream)
{
    const float* x   = (const float*)d_in[0];
    const float* W1  = (const float*)d_in[1];
    const float* b1  = (const float*)d_in[2];
    const float* g1  = (const float*)d_in[3];
    const float* be1 = (const float*)d_in[4];
    const float* W2  = (const float*)d_in[5];
    const float* b2  = (const float*)d_in[6];
    const float* g2  = (const float*)d_in[7];
    const float* be2 = (const float*)d_in[8];
    const float* W3  = (const float*)d_in[9];
    const float* b3  = (const float*)d_in[10];
    const float* g3  = (const float*)d_in[11];
    const float* be3 = (const float*)d_in[12];
    float* out = (float*)d_out;
    unsigned short* wp = (unsigned short*)d_ws;

    hipLaunchKernelGGL(pack_w_kernel, dim3(144), dim3(256), 0, stream, W1, W2, W3, wp);
    hipLaunchKernelGGL(edgeconv_mfma, dim3((Bdim * Ndim) / PTS), dim3(128), 0, stream,
                       x, wp, b1, g1, be1, b2, g2, be2, b3, g3, be3, out);
}

// Round 9
// 160.013 us; speedup vs baseline: 1.3193x; 1.0093x over previous
//
#include <hip/hip_runtime.h>
#include <math.h>

#define Bdim 64
#define Ndim 512
#define Ddim 16
#define Kdim 16
#define Edim 128
#define LN_EPS 1e-5f

#define PTS   2     // points per block, ONE point per wave
#define NT    8     // 16-wide N tiles over E=128
#define KS2   4     // 32-deep K steps over E=128

typedef __attribute__((ext_vector_type(8))) short bf16x8;
typedef __attribute__((ext_vector_type(4))) float f32x4;
typedef __attribute__((ext_vector_type(2))) float f32x2;

#if __has_builtin(__builtin_amdgcn_exp2f)
#define EXP2F __builtin_amdgcn_exp2f
#else
#define EXP2F exp2f
#endif

// ---- DPP helpers (pure VALU, no LDS) ----
// row_ror:N = 0x120|N ; ROW_BCAST15 = 0x142 ; ROW_BCAST31 = 0x143
template<int CTRL>
__device__ __forceinline__ unsigned dpp_u32(unsigned v) {
    return (unsigned)__builtin_amdgcn_update_dpp(0, (int)v, CTRL, 0xF, 0xF, true);
}
template<int CTRL>
__device__ __forceinline__ float dpp_f32(float v) {
    return __int_as_float(__builtin_amdgcn_update_dpp(0, __float_as_int(v), CTRL, 0xF, 0xF, true));
}
template<int CTRL>
__device__ __forceinline__ unsigned long long dpp_u64(unsigned long long v) {
    unsigned lo = dpp_u32<CTRL>((unsigned)v);
    unsigned hi = dpp_u32<CTRL>((unsigned)(v >> 32));
    return ((unsigned long long)hi << 32) | lo;
}
// keep-variant: lanes with no DPP source keep their own value (old = src, bound_ctrl=0)
template<int CTRL>
__device__ __forceinline__ unsigned long long dpp_u64_keep(unsigned long long v) {
    unsigned lo = (unsigned)__builtin_amdgcn_update_dpp(
        (int)(unsigned)v, (int)(unsigned)v, CTRL, 0xF, 0xF, false);
    unsigned hi = (unsigned)__builtin_amdgcn_update_dpp(
        (int)(unsigned)(v >> 32), (int)(unsigned)(v >> 32), CTRL, 0xF, 0xF, false);
    return ((unsigned long long)hi << 32) | lo;
}
__device__ __forceinline__ unsigned long long min_u64(unsigned long long a, unsigned long long b) {
    return (b < a) ? b : a;
}

// RNE float -> bf16 bits (used only in the tiny pack kernel)
__device__ __forceinline__ unsigned short f2bf(float f) {
    unsigned u = __float_as_uint(f);
    unsigned r = (u + 0x7FFFu + ((u >> 16) & 1u)) >> 16;
    return (unsigned short)r;
}

// HW packed f32->bf16 (RNE): lo16 = bf16(a), hi16 = bf16(b)
__device__ __forceinline__ unsigned cvt_pk_bf16(float a, float b) {
    unsigned r;
    asm("v_cvt_pk_bf16_f32 %0, %1, %2" : "=v"(r) : "v"(a), "v"(b));
    return r;
}

// packed GELU (tanh-form via sigmoid, exp folded to native 2^x):
// gelu(x) ~= x * rcp(1 + 2^(x * (-2.30220821 - 0.10294324 x^2)))
__device__ __forceinline__ f32x2 gelu2(f32x2 x) {
    f32x2 x2 = x * x;
    f32x2 t  = x2 * (f32x2){-0.10294324f, -0.10294324f}
                  + (f32x2){-2.30220821f, -2.30220821f};
    f32x2 z  = x * t;
    f32x2 e  = { EXP2F(z.x), EXP2F(z.y) };
    f32x2 d  = e + (f32x2){1.0f, 1.0f};
    f32x2 r  = { __builtin_amdgcn_rcpf(d.x), __builtin_amdgcn_rcpf(d.y) };
    return x * r;
}

// ---------------- weight pre-pack: fp32 row-major [K][128] -> bf16 B-fragments
// layout: [nt][ks][lane][j], fragment elem j of lane l = W[ks*32 + 8*(l>>4)+j][nt*16 + (l&15)]
__global__ __launch_bounds__(256) void pack_w_kernel(
    const float* __restrict__ W1, const float* __restrict__ W2,
    const float* __restrict__ W3, unsigned short* __restrict__ wp)
{
    int idx = blockIdx.x * 256 + threadIdx.x;
    if (idx >= 36864) return;
    if (idx < 4096) {
        int t = idx;
        int nt = t >> 9, l = (t >> 3) & 63, j = t & 7;
        int k = 8 * (l >> 4) + j, n = nt * 16 + (l & 15);
        wp[idx] = f2bf(W1[k * Edim + n]);
    } else if (idx < 20480) {
        int t = idx - 4096;
        int nt = t >> 11, ks = (t >> 9) & 3, l = (t >> 3) & 63, j = t & 7;
        int k = ks * 32 + 8 * (l >> 4) + j, n = nt * 16 + (l & 15);
        wp[idx] = f2bf(W2[k * Edim + n]);
    } else {
        int t = idx - 20480;
        int nt = t >> 11, ks = (t >> 9) & 3, l = (t >> 3) & 63, j = t & 7;
        int k = ks * 32 + 8 * (l >> 4) + j, n = nt * 16 + (l & 15);
        wp[idx] = f2bf(W3[k * Edim + n]);
    }
}

// LayerNorm + GELU on the wave-private accumulator (one point).
// D layout per 16x16 tile: value j of lane l is H[row = 4*(l>>4) + j][col = nt*16 + (l&15)]
// Row-reduction via packed DPP rot-adds; elementwise math on packed f32x2 (v_pk_*).
__device__ __forceinline__ void ln_gelu_acc(
    f32x4 acc[NT], const float* __restrict__ g, const float* __restrict__ be, int lane)
{
    const int cl = lane & 15;
    f32x2 s01 = {0.f,0.f}, s23 = {0.f,0.f}, q01 = {0.f,0.f}, q23 = {0.f,0.f};
    #pragma unroll
    for (int nt = 0; nt < NT; ++nt) {
        f32x2 a01 = { acc[nt][0], acc[nt][1] };
        f32x2 a23 = { acc[nt][2], acc[nt][3] };
        s01 += a01;  q01 += a01 * a01;      // pk_add / pk_fma
        s23 += a23;  q23 += a23 * a23;
    }
    // packed DPP rot-reduce over the 16 lanes of the row: 2 dpp + 1 pk_add per pair
    #define ROTSTEP(C) {                                                     \
        f32x2 t_;                                                            \
        t_.x = dpp_f32<C>(s01.x); t_.y = dpp_f32<C>(s01.y); s01 += t_;       \
        t_.x = dpp_f32<C>(s23.x); t_.y = dpp_f32<C>(s23.y); s23 += t_;       \
        t_.x = dpp_f32<C>(q01.x); t_.y = dpp_f32<C>(q01.y); q01 += t_;       \
        t_.x = dpp_f32<C>(q23.x); t_.y = dpp_f32<C>(q23.y); q23 += t_;       \
    }
    ROTSTEP(0x121) ROTSTEP(0x122) ROTSTEP(0x124) ROTSTEP(0x128)
    #undef ROTSTEP

    const f32x2 inv128 = { 1.0f/128.0f, 1.0f/128.0f };
    f32x2 m01 = s01 * inv128, m23 = s23 * inv128;
    f32x2 v01 = q01 * inv128 - m01 * m01;
    f32x2 v23 = q23 * inv128 - m23 * m23;
    f32x2 r01 = { __builtin_amdgcn_rsqf(v01.x + LN_EPS), __builtin_amdgcn_rsqf(v01.y + LN_EPS) };
    f32x2 r23 = { __builtin_amdgcn_rsqf(v23.x + LN_EPS), __builtin_amdgcn_rsqf(v23.y + LN_EPS) };

    #pragma unroll
    for (int nt = 0; nt < NT; ++nt) {
        const float gv = g[nt*16 + cl], bev = be[nt*16 + cl];
        const f32x2 gg = { gv, gv }, bb = { bev, bev };
        f32x2 a01 = { acc[nt][0], acc[nt][1] };
        f32x2 a23 = { acc[nt][2], acc[nt][3] };
        f32x2 w01 = (a01 - m01) * r01;
        f32x2 w23 = (a23 - m23) * r23;
        w01 = w01 * gg + bb;                // pk_fma
        w23 = w23 * gg + bb;
        w01 = gelu2(w01);
        w23 = gelu2(w23);
        acc[nt][0] = w01.x; acc[nt][1] = w01.y;
        acc[nt][2] = w23.x; acc[nt][3] = w23.y;
    }
}

// store acc (bf16 via HW cvt_pk) to swizzled H:
// elem col c of row r lives at r*128 + ((c>>3 ^ (r&7))<<3) + (c&7)
__device__ __forceinline__ void store_h(
    const f32x4 acc[NT], unsigned short* __restrict__ s_h, int wave, int lane)
{
    const int cl = lane & 15, gq = lane >> 4;
    const int rbase = 16*wave + 4*gq;
    #pragma unroll
    for (int nt = 0; nt < NT; ++nt) {
        const int col = nt*16 + cl;
        const int cb  = col >> 3;
        const unsigned r01 = cvt_pk_bf16(acc[nt][0], acc[nt][1]);
        const unsigned r23 = cvt_pk_bf16(acc[nt][2], acc[nt][3]);
        const int a0 = (rbase+0)*128 + ((cb ^ ((rbase+0) & 7)) << 3) + (col & 7);
        const int a1 = (rbase+1)*128 + ((cb ^ ((rbase+1) & 7)) << 3) + (col & 7);
        const int a2 = (rbase+2)*128 + ((cb ^ ((rbase+2) & 7)) << 3) + (col & 7);
        const int a3 = (rbase+3)*128 + ((cb ^ ((rbase+3) & 7)) << 3) + (col & 7);
        s_h[a0] = (unsigned short)(r01 & 0xFFFFu);
        s_h[a1] = (unsigned short)(r01 >> 16);
        s_h[a2] = (unsigned short)(r23 & 0xFFFFu);
        s_h[a3] = (unsigned short)(r23 >> 16);
    }
}

__global__ __launch_bounds__(128, 4) void edgeconv_mfma(
    const float* __restrict__ x,
    const unsigned short* __restrict__ wp,
    const float* __restrict__ b1, const float* __restrict__ g1, const float* __restrict__ be1,
    const float* __restrict__ b2, const float* __restrict__ g2, const float* __restrict__ be2,
    const float* __restrict__ b3, const float* __restrict__ g3, const float* __restrict__ be3,
    float* __restrict__ out)
{
    const int tid  = threadIdx.x;
    const int wave = tid >> 6, lane = tid & 63;
    const int bp = blockIdx.x;
    const int b  = bp >> 8;              // 256 blocks per batch element
    const int n0 = (bp & 255) * PTS;
    const int n  = n0 + wave;            // this wave's point

    // only LDS: wave-private H rows (wave w owns rows 16w..16w+15). No barriers anywhere.
    __shared__ __align__(16) unsigned short s_h[32 * 128];         // 8 KB, XOR-swizzled

    const float* __restrict__ xb = x + (size_t)b * (Ndim * Ddim);
    const int cl = lane & 15, gq = lane >> 4;

    // ---- KNN for this wave's point. Exact fp32 mul/mul/add; ties by lower idx.
    //      Lane cl captures the cl-th selected neighbor index in my_nb.
    unsigned my_nb = 0;
    {
        const float qx = xb[n * Ddim + 8], qy = xb[n * Ddim + 9];
        unsigned long long key[8];
        #pragma unroll
        for (int c = 0; c < 8; ++c) {
            int j = c * 64 + lane;
            const float2 p2 = *(const float2*)(xb + j * Ddim + 8);
            float dx = __fsub_rn(qx, p2.x);
            float dy = __fsub_rn(qy, p2.y);
            float d2 = __fadd_rn(__fmul_rn(dx,dx), __fmul_rn(dy,dy));
            key[c] = ((unsigned long long)__float_as_uint(d2) << 32) | (unsigned)j;
        }
        // lane-local ascending sort of 8 keys (Batcher odd-even mergesort, 19 CE)
        #define CE(A,B) { bool c_ = key[A] < key[B];                          \
                          unsigned long long lo_ = c_ ? key[A] : key[B];      \
                          unsigned long long hi_ = c_ ? key[B] : key[A];      \
                          key[A] = lo_; key[B] = hi_; }
        CE(0,1) CE(2,3) CE(4,5) CE(6,7)
        CE(0,2) CE(1,3) CE(4,6) CE(5,7)
        CE(1,2) CE(5,6)
        CE(0,4) CE(1,5) CE(2,6) CE(3,7)
        CE(2,4) CE(3,5)
        CE(1,2) CE(3,4) CE(5,6)
        #undef CE

        #pragma unroll
        for (int sel = 0; sel < Kdim; ++sel) {
            unsigned long long m = key[0];          // lane-local current min (sorted head)
            // intra-row min via DPP rotations: all 16 lanes of each row get the row min
            m = min_u64(m, dpp_u64<0x121>(m));
            m = min_u64(m, dpp_u64<0x122>(m));
            m = min_u64(m, dpp_u64<0x124>(m));
            m = min_u64(m, dpp_u64<0x128>(m));
            // cross-row fold, still VALU-only:
            // bcast15: rows 1,3 receive row0/row2 min -> lanes 16-31 = min(r0,r1), 48-63 = min(r2,r3)
            m = min_u64(m, dpp_u64_keep<0x142>(m));
            // bcast31: lanes 32-63 receive lane31 (= min(r0,r1)) -> lanes 48-63 = global min
            m = min_u64(m, dpp_u64_keep<0x143>(m));
            // broadcast the winner to all lanes through SGPRs
            const unsigned wlo = (unsigned)__builtin_amdgcn_readlane((int)(unsigned)m, 63);
            const unsigned whi = (unsigned)__builtin_amdgcn_readlane((int)(unsigned)(m >> 32), 63);
            const unsigned long long skey = ((unsigned long long)whi << 32) | wlo;
            if ((lane & 15) == sel) my_nb = wlo;    // winner idx, captured in all 4 quads
            if (key[0] == skey) {                   // unique owner pops its sorted head
                key[0] = key[1]; key[1] = key[2]; key[2] = key[3]; key[3] = key[4];
                key[4] = key[5]; key[5] = key[6]; key[6] = key[7]; key[7] = ~0ull;
            }
        }
    }

    f32x4 acc[NT];

    // ================= Layer 1: feats(16x32) @ W1, A-fragment built in registers =================
    {
        const int off8 = (gq & 1) * 8;
        const float* pc = xb + n * Ddim + off8;
        const float* pn = xb + (int)my_nb * Ddim + off8;
        float4 c0 = *(const float4*)(pc);
        float4 c1 = *(const float4*)(pc + 4);
        float4 v0 = *(const float4*)(pn);
        float4 v1 = *(const float4*)(pn + 4);
        const bool diff = (gq >= 2);
        float e0 = diff ? (v0.x - c0.x) : c0.x;
        float e1 = diff ? (v0.y - c0.y) : c0.y;
        float e2 = diff ? (v0.z - c0.z) : c0.z;
        float e3 = diff ? (v0.w - c0.w) : c0.w;
        float e4 = diff ? (v1.x - c1.x) : c1.x;
        float e5 = diff ? (v1.y - c1.y) : c1.y;
        float e6 = diff ? (v1.z - c1.z) : c1.z;
        float e7 = diff ? (v1.w - c1.w) : c1.w;
        union { unsigned u[4]; bf16x8 v; } a1u;
        a1u.u[0] = cvt_pk_bf16(e0, e1);
        a1u.u[1] = cvt_pk_bf16(e2, e3);
        a1u.u[2] = cvt_pk_bf16(e4, e5);
        a1u.u[3] = cvt_pk_bf16(e6, e7);
        const bf16x8 a1 = a1u.v;

        #pragma unroll
        for (int nt = 0; nt < NT; ++nt) {
            const float bv = b1[nt*16 + cl];
            bf16x8 bfr = *(const bf16x8*)(wp + (nt*64 + lane)*8);
            f32x4 c = {bv, bv, bv, bv};
            acc[nt] = __builtin_amdgcn_mfma_f32_16x16x32_bf16(a1, bfr, c, 0, 0, 0);
        }
    }
    ln_gelu_acc(acc, g1, be1, lane);
    store_h(acc, s_h, wave, lane);

    // ================= Layers 2 and 3: H(16x128) @ W(128x128) =================
    #pragma unroll 1
    for (int layer = 0; layer < 2; ++layer) {
        const unsigned short* wpL = wp + (layer == 0 ? 4096 : 20480);
        const float* bL  = (layer == 0) ? b2  : b3;
        const float* gL  = (layer == 0) ? g2  : g3;
        const float* beL = (layer == 0) ? be2 : be3;

        bf16x8 a[KS2];
        {
            const int row = 16*wave + cl;
            #pragma unroll
            for (int ks = 0; ks < KS2; ++ks) {
                const int cb = ks*4 + gq;
                a[ks] = *(const bf16x8*)(&s_h[row*128 + ((cb ^ (row & 7)) << 3)]);
            }
        }
        #pragma unroll
        for (int nt = 0; nt < NT; ++nt) {
            const float bv = bL[nt*16 + cl];
            f32x4 c = {bv, bv, bv, bv};
            #pragma unroll
            for (int ks = 0; ks < KS2; ++ks) {
                bf16x8 bfr = *(const bf16x8*)(wpL + ((nt*KS2 + ks)*64 + lane)*8);
                c = __builtin_amdgcn_mfma_f32_16x16x32_bf16(a[ks], bfr, c, 0, 0, 0);
            }
            acc[nt] = c;
        }
        ln_gelu_acc(acc, gL, beL, lane);
        if (layer == 0) store_h(acc, s_h, wave, lane);
    }

    // ================= mean over K=16 rows, write out =================
    #pragma unroll
    for (int nt = 0; nt < NT; ++nt) {
        f32x2 p = { acc[nt][0], acc[nt][1] };
        f32x2 q = { acc[nt][2], acc[nt][3] };
        f32x2 h = p + q;                    // pk_add
        float sv = h.x + h.y;
        sv += __shfl_xor(sv, 16, 64);
        sv += __shfl_xor(sv, 32, 64);
        if (gq == (nt >> 1))    // 16 lanes of the owning quad write 64B
            out[((size_t)b * Ndim + n) * Edim + nt*16 + cl] = sv * (1.0f/16.0f);
    }
}

extern "C" void kernel_launch(void* const* d_in, const int* in_sizes, int n_in,
                              void* d_out, int out_size, void* d_ws, size_t ws_size,
                              hipStream_t stream)
{
    const float* x   = (const float*)d_in[0];
    const float* W1  = (const float*)d_in[1];
    const float* b1  = (const float*)d_in[2];
    const float* g1  = (const float*)d_in[3];
    const float* be1 = (const float*)d_in[4];
    const float* W2  = (const float*)d_in[5];
    const float* b2  = (const float*)d_in[6];
    const float* g2  = (const float*)d_in[7];
    const float* be2 = (const float*)d_in[8];
    const float* W3  = (const float*)d_in[9];
    const float* b3  = (const float*)d_in[10];
    const float* g3  = (const float*)d_in[11];
    const float* be3 = (const float*)d_in[12];
    float* out = (float*)d_out;
    unsigned short* wp = (unsigned short*)d_ws;

    hipLaunchKernelGGL(pack_w_kernel, dim3(144), dim3(256), 0, stream, W1, W2, W3, wp);
    hipLaunchKernelGGL(edgeconv_mfma, dim3((Bdim * Ndim) / PTS), dim3(128), 0, stream,
                       x, wp, b1, g1, be1, b2, g2, be2, b3, g3, be3, out);
}

// Round 10
// 158.346 us; speedup vs baseline: 1.3332x; 1.0105x over previous
//
#include <hip/hip_runtime.h>
#include <math.h>

#define Bdim 64
#define Ndim 512
#define Ddim 16
#define Kdim 16
#define Edim 128
#define LN_EPS 1e-5f

#define PTS   2     // points per block, ONE point per wave
#define NT    8     // 16-wide N tiles over E=128
#define KS2   4     // 32-deep K steps over E=128

typedef __attribute__((ext_vector_type(8))) short bf16x8;
typedef __attribute__((ext_vector_type(4))) float f32x4;
typedef __attribute__((ext_vector_type(2))) float f32x2;

#if __has_builtin(__builtin_amdgcn_exp2f)
#define EXP2F __builtin_amdgcn_exp2f
#else
#define EXP2F exp2f
#endif

// ---- DPP helpers (pure VALU, no LDS) ----
// row_ror:N = 0x120|N ; ROW_BCAST15 = 0x142 ; ROW_BCAST31 = 0x143
template<int CTRL>
__device__ __forceinline__ unsigned dpp_u32(unsigned v) {
    return (unsigned)__builtin_amdgcn_update_dpp(0, (int)v, CTRL, 0xF, 0xF, true);
}
// keep-variant: lanes with no DPP source keep their own value (old = src, bound_ctrl=0)
template<int CTRL>
__device__ __forceinline__ unsigned dpp_u32_keep(unsigned v) {
    return (unsigned)__builtin_amdgcn_update_dpp((int)v, (int)v, CTRL, 0xF, 0xF, false);
}
template<int CTRL>
__device__ __forceinline__ float dpp_f32(float v) {
    return __int_as_float(__builtin_amdgcn_update_dpp(0, __float_as_int(v), CTRL, 0xF, 0xF, true));
}
__device__ __forceinline__ unsigned min_u32(unsigned a, unsigned b) { return (b < a) ? b : a; }

// RNE float -> bf16 bits (used only in the tiny pack kernel)
__device__ __forceinline__ unsigned short f2bf(float f) {
    unsigned u = __float_as_uint(f);
    unsigned r = (u + 0x7FFFu + ((u >> 16) & 1u)) >> 16;
    return (unsigned short)r;
}

// HW packed f32->bf16 (RNE): lo16 = bf16(a), hi16 = bf16(b)
__device__ __forceinline__ unsigned cvt_pk_bf16(float a, float b) {
    unsigned r;
    asm("v_cvt_pk_bf16_f32 %0, %1, %2" : "=v"(r) : "v"(a), "v"(b));
    return r;
}

// packed GELU (tanh-form via sigmoid, exp folded to native 2^x):
// gelu(x) ~= x * rcp(1 + 2^(x * (-2.30220821 - 0.10294324 x^2)))
__device__ __forceinline__ f32x2 gelu2(f32x2 x) {
    f32x2 x2 = x * x;
    f32x2 t  = x2 * (f32x2){-0.10294324f, -0.10294324f}
                  + (f32x2){-2.30220821f, -2.30220821f};
    f32x2 z  = x * t;
    f32x2 e  = { EXP2F(z.x), EXP2F(z.y) };
    f32x2 d  = e + (f32x2){1.0f, 1.0f};
    f32x2 r  = { __builtin_amdgcn_rcpf(d.x), __builtin_amdgcn_rcpf(d.y) };
    return x * r;
}

// ---------------- weight pre-pack ----------------
// wp[0..36863]  : bf16 B-fragments (layout as before)
// fp32 at float index 18432 (byte 73728): gbe pairs, float2
//   gbe[((lay*8 + nt)*16 + cl)] = { g[nt*16+cl], be[nt*16+cl] }   (768 floats)
__global__ __launch_bounds__(256) void pack_w_kernel(
    const float* __restrict__ W1, const float* __restrict__ W2,
    const float* __restrict__ W3,
    const float* __restrict__ g1, const float* __restrict__ be1,
    const float* __restrict__ g2, const float* __restrict__ be2,
    const float* __restrict__ g3, const float* __restrict__ be3,
    unsigned short* __restrict__ wp)
{
    int idx = blockIdx.x * 256 + threadIdx.x;
    if (idx >= 37632) return;
    if (idx < 4096) {
        int t = idx;
        int nt = t >> 9, l = (t >> 3) & 63, j = t & 7;
        int k = 8 * (l >> 4) + j, n = nt * 16 + (l & 15);
        wp[idx] = f2bf(W1[k * Edim + n]);
    } else if (idx < 20480) {
        int t = idx - 4096;
        int nt = t >> 11, ks = (t >> 9) & 3, l = (t >> 3) & 63, j = t & 7;
        int k = ks * 32 + 8 * (l >> 4) + j, n = nt * 16 + (l & 15);
        wp[idx] = f2bf(W2[k * Edim + n]);
    } else if (idx < 36864) {
        int t = idx - 20480;
        int nt = t >> 11, ks = (t >> 9) & 3, l = (t >> 3) & 63, j = t & 7;
        int k = ks * 32 + 8 * (l >> 4) + j, n = nt * 16 + (l & 15);
        wp[idx] = f2bf(W3[k * Edim + n]);
    } else {
        int t = idx - 36864;              // 0..767
        int lay = t >> 8;                 // 256 floats per layer
        int e   = t & 255;
        int nt  = e >> 5;                 // 32 per nt (16 cl x 2 comp)
        int cl  = (e >> 1) & 15;
        int comp = e & 1;
        const float* g  = (lay == 0) ? g1  : (lay == 1) ? g2  : g3;
        const float* be = (lay == 0) ? be1 : (lay == 1) ? be2 : be3;
        float v = comp ? be[nt*16 + cl] : g[nt*16 + cl];
        ((float*)wp)[18432 + t] = v;
    }
}

// LayerNorm + GELU on the wave-private accumulator (one point).
// D layout per 16x16 tile: value j of lane l is H[row = 4*(l>>4) + j][col = nt*16 + (l&15)]
// Row-reduction via packed DPP rot-adds; elementwise math on packed f32x2 (v_pk_*).
// gbeL: per-layer {gamma, beta} pairs, indexed [nt*16 + cl].
__device__ __forceinline__ void ln_gelu_acc(
    f32x4 acc[NT], const float2* __restrict__ gbeL, int lane)
{
    const int cl = lane & 15;
    f32x2 s01 = {0.f,0.f}, s23 = {0.f,0.f}, q01 = {0.f,0.f}, q23 = {0.f,0.f};
    #pragma unroll
    for (int nt = 0; nt < NT; ++nt) {
        f32x2 a01 = { acc[nt][0], acc[nt][1] };
        f32x2 a23 = { acc[nt][2], acc[nt][3] };
        s01 += a01;  q01 += a01 * a01;      // pk_add / pk_fma
        s23 += a23;  q23 += a23 * a23;
    }
    #define ROTSTEP(C) {                                                     \
        f32x2 t_;                                                            \
        t_.x = dpp_f32<C>(s01.x); t_.y = dpp_f32<C>(s01.y); s01 += t_;       \
        t_.x = dpp_f32<C>(s23.x); t_.y = dpp_f32<C>(s23.y); s23 += t_;       \
        t_.x = dpp_f32<C>(q01.x); t_.y = dpp_f32<C>(q01.y); q01 += t_;       \
        t_.x = dpp_f32<C>(q23.x); t_.y = dpp_f32<C>(q23.y); q23 += t_;       \
    }
    ROTSTEP(0x121) ROTSTEP(0x122) ROTSTEP(0x124) ROTSTEP(0x128)
    #undef ROTSTEP

    const f32x2 inv128 = { 1.0f/128.0f, 1.0f/128.0f };
    f32x2 m01 = s01 * inv128, m23 = s23 * inv128;
    f32x2 v01 = q01 * inv128 - m01 * m01;
    f32x2 v23 = q23 * inv128 - m23 * m23;
    f32x2 r01 = { __builtin_amdgcn_rsqf(v01.x + LN_EPS), __builtin_amdgcn_rsqf(v01.y + LN_EPS) };
    f32x2 r23 = { __builtin_amdgcn_rsqf(v23.x + LN_EPS), __builtin_amdgcn_rsqf(v23.y + LN_EPS) };

    #pragma unroll
    for (int nt = 0; nt < NT; ++nt) {
        const float2 gb = gbeL[nt*16 + cl];       // one dwordx2: {gamma, beta}
        const f32x2 gg = { gb.x, gb.x }, bb = { gb.y, gb.y };
        f32x2 a01 = { acc[nt][0], acc[nt][1] };
        f32x2 a23 = { acc[nt][2], acc[nt][3] };
        f32x2 w01 = (a01 - m01) * r01;
        f32x2 w23 = (a23 - m23) * r23;
        w01 = w01 * gg + bb;                // pk_fma
        w23 = w23 * gg + bb;
        w01 = gelu2(w01);
        w23 = gelu2(w23);
        acc[nt][0] = w01.x; acc[nt][1] = w01.y;
        acc[nt][2] = w23.x; acc[nt][3] = w23.y;
    }
}

// store acc (bf16 via HW cvt_pk) to swizzled H:
// elem col c of row r lives at r*128 + ((c>>3 ^ (r&7))<<3) + (c&7)
__device__ __forceinline__ void store_h(
    const f32x4 acc[NT], unsigned short* __restrict__ s_h, int wave, int lane)
{
    const int cl = lane & 15, gq = lane >> 4;
    const int rbase = 16*wave + 4*gq;
    #pragma unroll
    for (int nt = 0; nt < NT; ++nt) {
        const int col = nt*16 + cl;
        const int cb  = col >> 3;
        const unsigned r01 = cvt_pk_bf16(acc[nt][0], acc[nt][1]);
        const unsigned r23 = cvt_pk_bf16(acc[nt][2], acc[nt][3]);
        const int a0 = (rbase+0)*128 + ((cb ^ ((rbase+0) & 7)) << 3) + (col & 7);
        const int a1 = (rbase+1)*128 + ((cb ^ ((rbase+1) & 7)) << 3) + (col & 7);
        const int a2 = (rbase+2)*128 + ((cb ^ ((rbase+2) & 7)) << 3) + (col & 7);
        const int a3 = (rbase+3)*128 + ((cb ^ ((rbase+3) & 7)) << 3) + (col & 7);
        s_h[a0] = (unsigned short)(r01 & 0xFFFFu);
        s_h[a1] = (unsigned short)(r01 >> 16);
        s_h[a2] = (unsigned short)(r23 & 0xFFFFu);
        s_h[a3] = (unsigned short)(r23 >> 16);
    }
}

__global__ __launch_bounds__(128, 4) void edgeconv_mfma(
    const float* __restrict__ x,
    const unsigned short* __restrict__ wp,
    const float* __restrict__ b1, const float* __restrict__ b2,
    const float* __restrict__ b3,
    float* __restrict__ out)
{
    const int tid  = threadIdx.x;
    const int wave = tid >> 6, lane = tid & 63;
    const int bp = blockIdx.x;
    const int b  = bp >> 8;              // 256 blocks per batch element
    const int n0 = (bp & 255) * PTS;
    const int n  = n0 + wave;            // this wave's point

    // only LDS: wave-private H rows (wave w owns rows 16w..16w+15). No barriers anywhere.
    __shared__ __align__(16) unsigned short s_h[32 * 128];         // 8 KB, XOR-swizzled

    const float* __restrict__ xb = x + (size_t)b * (Ndim * Ddim);
    const float2* __restrict__ gbep = (const float2*)((const float*)wp + 18432);
    const int cl = lane & 15, gq = lane >> 4;

    // ---- KNN for this wave's point. Exact fp32 mul/mul/add; lex (d2, idx) order.
    //      Lane cl captures the cl-th selected neighbor index in my_nb.
    unsigned my_nb = 0;
    {
        const float qx = xb[n * Ddim + 8], qy = xb[n * Ddim + 9];
        unsigned long long key[8];
        #pragma unroll
        for (int c = 0; c < 8; ++c) {
            int j = c * 64 + lane;
            const float2 p2 = *(const float2*)(xb + j * Ddim + 8);
            float dx = __fsub_rn(qx, p2.x);
            float dy = __fsub_rn(qy, p2.y);
            float d2 = __fadd_rn(__fmul_rn(dx,dx), __fmul_rn(dy,dy));
            key[c] = ((unsigned long long)__float_as_uint(d2) << 32) | (unsigned)j;
        }
        // lane-local ascending sort of 8 keys (Batcher odd-even mergesort, 19 CE)
        #define CE(A,B) { bool c_ = key[A] < key[B];                          \
                          unsigned long long lo_ = c_ ? key[A] : key[B];      \
                          unsigned long long hi_ = c_ ? key[B] : key[A];      \
                          key[A] = lo_; key[B] = hi_; }
        CE(0,1) CE(2,3) CE(4,5) CE(6,7)
        CE(0,2) CE(1,3) CE(4,6) CE(5,7)
        CE(1,2) CE(5,6)
        CE(0,4) CE(1,5) CE(2,6) CE(3,7)
        CE(2,4) CE(3,5)
        CE(1,2) CE(3,4) CE(5,6)
        #undef CE

        unsigned d2h[8], idxh[8];
        #pragma unroll
        for (int c = 0; c < 8; ++c) {
            d2h[c]  = (unsigned)(key[c] >> 32);
            idxh[c] = (unsigned)key[c];
        }

        #pragma unroll
        for (int sel = 0; sel < Kdim; ++sel) {
            // wave-min of head d2: u32 only (1 v_min_u32 per stage)
            unsigned m = d2h[0];
            m = min_u32(m, dpp_u32<0x121>(m));
            m = min_u32(m, dpp_u32<0x122>(m));
            m = min_u32(m, dpp_u32<0x124>(m));
            m = min_u32(m, dpp_u32<0x128>(m));
            m = min_u32(m, dpp_u32_keep<0x142>(m));   // row1/3 <- min with row0/2
            m = min_u32(m, dpp_u32_keep<0x143>(m));   // upper half <- min with lane31
            const unsigned gmin = (unsigned)__builtin_amdgcn_readlane((int)m, 63);

            // tie resolution: wave-uniform branch, multi-tie is ~1e-4 rare
            const unsigned long long tied = __ballot(d2h[0] == gmin);
            unsigned widx;
            if (__popcll(tied) == 1) {
                const int s = (int)(__ffsll((long long)tied) - 1);
                widx = (unsigned)__builtin_amdgcn_readlane((int)idxh[0], s);
            } else {
                unsigned t = (d2h[0] == gmin) ? idxh[0] : 0xFFFFFFFFu;
                t = min_u32(t, dpp_u32<0x121>(t));
                t = min_u32(t, dpp_u32<0x122>(t));
                t = min_u32(t, dpp_u32<0x124>(t));
                t = min_u32(t, dpp_u32<0x128>(t));
                t = min_u32(t, dpp_u32_keep<0x142>(t));
                t = min_u32(t, dpp_u32_keep<0x143>(t));
                widx = (unsigned)__builtin_amdgcn_readlane((int)t, 63);
            }
            if ((lane & 15) == sel) my_nb = widx;     // capture in all 4 quads
            if (sel < Kdim - 1) {
                if (d2h[0] == gmin && idxh[0] == widx) {   // unique owner pops head
                    d2h[0]=d2h[1]; d2h[1]=d2h[2]; d2h[2]=d2h[3]; d2h[3]=d2h[4];
                    d2h[4]=d2h[5]; d2h[5]=d2h[6]; d2h[6]=d2h[7]; d2h[7]=0xFFFFFFFFu;
                    idxh[0]=idxh[1]; idxh[1]=idxh[2]; idxh[2]=idxh[3]; idxh[3]=idxh[4];
                    idxh[4]=idxh[5]; idxh[5]=idxh[6]; idxh[6]=idxh[7];
                }
            }
        }
    }

    f32x4 acc[NT];

    // ================= Layer 1: feats(16x32) @ W1, A-fragment built in registers =================
    {
        const int off8 = (gq & 1) * 8;
        const float* pc = xb + n * Ddim + off8;
        const float* pn = xb + (int)my_nb * Ddim + off8;
        float4 c0 = *(const float4*)(pc);
        float4 c1 = *(const float4*)(pc + 4);
        float4 v0 = *(const float4*)(pn);
        float4 v1 = *(const float4*)(pn + 4);
        const bool diff = (gq >= 2);
        float e0 = diff ? (v0.x - c0.x) : c0.x;
        float e1 = diff ? (v0.y - c0.y) : c0.y;
        float e2 = diff ? (v0.z - c0.z) : c0.z;
        float e3 = diff ? (v0.w - c0.w) : c0.w;
        float e4 = diff ? (v1.x - c1.x) : c1.x;
        float e5 = diff ? (v1.y - c1.y) : c1.y;
        float e6 = diff ? (v1.z - c1.z) : c1.z;
        float e7 = diff ? (v1.w - c1.w) : c1.w;
        union { unsigned u[4]; bf16x8 v; } a1u;
        a1u.u[0] = cvt_pk_bf16(e0, e1);
        a1u.u[1] = cvt_pk_bf16(e2, e3);
        a1u.u[2] = cvt_pk_bf16(e4, e5);
        a1u.u[3] = cvt_pk_bf16(e6, e7);
        const bf16x8 a1 = a1u.v;

        #pragma unroll
        for (int nt = 0; nt < NT; ++nt) {
            const float bv = b1[nt*16 + cl];
            bf16x8 bfr = *(const bf16x8*)(wp + (nt*64 + lane)*8);
            f32x4 c = {bv, bv, bv, bv};
            acc[nt] = __builtin_amdgcn_mfma_f32_16x16x32_bf16(a1, bfr, c, 0, 0, 0);
        }
    }
    ln_gelu_acc(acc, gbep, lane);
    store_h(acc, s_h, wave, lane);

    // ================= Layers 2 and 3: H(16x128) @ W(128x128) =================
    #pragma unroll 1
    for (int layer = 0; layer < 2; ++layer) {
        const unsigned short* wpL = wp + (layer == 0 ? 4096 : 20480);
        const float* bL = (layer == 0) ? b2 : b3;
        const float2* gbeL = gbep + (layer == 0 ? 128 : 256);

        bf16x8 a[KS2];
        {
            const int row = 16*wave + cl;
            #pragma unroll
            for (int ks = 0; ks < KS2; ++ks) {
                const int cb = ks*4 + gq;
                a[ks] = *(const bf16x8*)(&s_h[row*128 + ((cb ^ (row & 7)) << 3)]);
            }
        }
        #pragma unroll
        for (int nt = 0; nt < NT; ++nt) {
            const float bv = bL[nt*16 + cl];
            f32x4 c = {bv, bv, bv, bv};
            #pragma unroll
            for (int ks = 0; ks < KS2; ++ks) {
                bf16x8 bfr = *(const bf16x8*)(wpL + ((nt*KS2 + ks)*64 + lane)*8);
                c = __builtin_amdgcn_mfma_f32_16x16x32_bf16(a[ks], bfr, c, 0, 0, 0);
            }
            acc[nt] = c;
        }
        ln_gelu_acc(acc, gbeL, lane);
        if (layer == 0) store_h(acc, s_h, wave, lane);
    }

    // ================= mean over K=16 rows, write out =================
    #pragma unroll
    for (int nt = 0; nt < NT; ++nt) {
        f32x2 p = { acc[nt][0], acc[nt][1] };
        f32x2 q = { acc[nt][2], acc[nt][3] };
        f32x2 h = p + q;                    // pk_add
        float sv = h.x + h.y;
        sv += __shfl_xor(sv, 16, 64);
        sv += __shfl_xor(sv, 32, 64);
        if (gq == (nt >> 1))    // 16 lanes of the owning quad write 64B
            out[((size_t)b * Ndim + n) * Edim + nt*16 + cl] = sv * (1.0f/16.0f);
    }
}

extern "C" void kernel_launch(void* const* d_in, const int* in_sizes, int n_in,
                              void* d_out, int out_size, void* d_ws, size_t ws_size,
                              hipStream_t stream)
{
    const float* x   = (const float*)d_in[0];
    const float* W1  = (const float*)d_in[1];
    const float* b1  = (const float*)d_in[2];
    const float* g1  = (const float*)d_in[3];
    const float* be1 = (const float*)d_in[4];
    const float* W2  = (const float*)d_in[5];
    const float* b2  = (const float*)d_in[6];
    const float* g2  = (const float*)d_in[7];
    const float* be2 = (const float*)d_in[8];
    const float* W3  = (const float*)d_in[9];
    const float* b3  = (const float*)d_in[10];
    const float* g3  = (const float*)d_in[11];
    const float* be3 = (const float*)d_in[12];
    float* out = (float*)d_out;
    unsigned short* wp = (unsigned short*)d_ws;

    hipLaunchKernelGGL(pack_w_kernel, dim3(147), dim3(256), 0, stream,
                       W1, W2, W3, g1, be1, g2, be2, g3, be3, wp);
    hipLaunchKernelGGL(edgeconv_mfma, dim3((Bdim * Ndim) / PTS), dim3(128), 0, stream,
                       x, wp, b1, b2, b3, out);
}